// Round 2
// baseline (1229.725 us; speedup 1.0000x reference)
//
#include <hip/hip_runtime.h>
#include <hip/hip_bf16.h>
#include <math.h>

#define B_   16
#define C_   256
#define H_   64
#define W_   64
#define L_   1024   // 32*32 per quadrant
#define N_   64     // s*s*B
#define D_   8      // inter channels for q/k

typedef short bf16x8 __attribute__((ext_vector_type(8)));
typedef float f32x4  __attribute__((ext_vector_type(4)));

// ---------------------------------------------------------------------------
// Kernel 1: q/k projection.  q,k [N,8,L] = W[8,256] @ xb[N,256,L] + b
// ---------------------------------------------------------------------------
__global__ __launch_bounds__(256) void qk_proj(
    const float* __restrict__ x, const float* __restrict__ Wq,
    const float* __restrict__ bq, const float* __restrict__ Wk,
    const float* __restrict__ bk, float* __restrict__ q, float* __restrict__ k)
{
    __shared__ float Ws[16][C_];
    __shared__ float bs[16];
    int t = threadIdx.x;
    for (int i = t; i < 8 * C_; i += 256) {
        Ws[i >> 8][i & 255]       = Wq[i];
        Ws[8 + (i >> 8)][i & 255] = Wk[i];
    }
    if (t < 8) { bs[t] = bq[t]; bs[8 + t] = bk[t]; }
    __syncthreads();

    int gid = blockIdx.x * 256 + t;
    int n = gid >> 10, l = gid & 1023;
    int si = n >> 5, sj = (n >> 4) & 1, b = n & 15;
    int h = si * 32 + (l >> 5), w = sj * 32 + (l & 31);
    const float* xp = x + ((size_t)(b * C_) * H_ + h) * W_ + w;

    float acc[16];
    #pragma unroll
    for (int d = 0; d < 16; d++) acc[d] = bs[d];

    for (int c0 = 0; c0 < C_; c0 += 4) {
        float xv[4];
        #pragma unroll
        for (int u = 0; u < 4; u++) xv[u] = xp[(size_t)(c0 + u) * (H_ * W_)];
        #pragma unroll
        for (int d = 0; d < 16; d++) {
            float4 wv = *reinterpret_cast<const float4*>(&Ws[d][c0]);
            acc[d] += wv.x * xv[0] + wv.y * xv[1] + wv.z * xv[2] + wv.w * xv[3];
        }
    }
    #pragma unroll
    for (int d = 0; d < 8; d++) q[((size_t)n * 8 + d) * L_ + l] = acc[d];
    #pragma unroll
    for (int d = 0; d < 8; d++) k[((size_t)n * 8 + d) * L_ + l] = acc[8 + d];
}

// ---------------------------------------------------------------------------
// Kernel 2: v projection GEMM (fp32).  vt[n][l][c]
// ---------------------------------------------------------------------------
__global__ __launch_bounds__(256) void v_proj(
    const float* __restrict__ x, const float* __restrict__ Wv,
    const float* __restrict__ bv, float* __restrict__ vt)
{
    int n = blockIdx.x;
    int l0 = blockIdx.y * 128;
    int c0 = blockIdx.z * 128;
    int si = n >> 5, sj = (n >> 4) & 1, b = n & 15;
    __shared__ float Xs[16][132];
    __shared__ float Ws[16][132];
    int t = threadIdx.x;
    int lr = t & 15, cr = t >> 4;
    float acc[8][8] = {};
    const size_t HW = (size_t)H_ * W_;

    for (int k0 = 0; k0 < C_; k0 += 16) {
        for (int idx = t; idx < 16 * 128; idx += 256) {
            int kk = idx >> 7, ll = idx & 127;
            int l = l0 + ll;
            int h = si * 32 + (l >> 5), w = sj * 32 + (l & 31);
            Xs[kk][ll] = x[((size_t)(b * C_ + k0 + kk)) * HW + h * W_ + w];
        }
        for (int idx = t; idx < 16 * 128; idx += 256) {
            int cc = idx >> 4, kk = idx & 15;
            Ws[kk][cc] = Wv[(size_t)(c0 + cc) * C_ + k0 + kk];
        }
        __syncthreads();
        #pragma unroll 4
        for (int kk = 0; kk < 16; kk++) {
            float a[8], bb[8];
            #pragma unroll
            for (int r = 0; r < 8; r++) a[r] = Xs[kk][lr * 8 + r];
            #pragma unroll
            for (int j = 0; j < 8; j++) bb[j] = Ws[kk][cr * 8 + j];
            #pragma unroll
            for (int r = 0; r < 8; r++)
                #pragma unroll
                for (int j = 0; j < 8; j++) acc[r][j] += a[r] * bb[j];
        }
        __syncthreads();
    }
    float bias[8];
    #pragma unroll
    for (int j = 0; j < 8; j++) bias[j] = bv[c0 + cr * 8 + j];
    #pragma unroll
    for (int r = 0; r < 8; r++) {
        int l = l0 + lr * 8 + r;
        float* o = vt + ((size_t)n * L_ + l) * C_ + c0 + cr * 8;
        #pragma unroll
        for (int j = 0; j < 8; j++) o[j] = acc[r][j] + bias[j];
    }
}

// ---------------------------------------------------------------------------
// Kernel 3: flash attention + gamma_nl residual -> ctx hi/lo bf16, chan-last
// ---------------------------------------------------------------------------
__global__ __launch_bounds__(256) void attn_kernel(
    const float* __restrict__ x, const float* __restrict__ q,
    const float* __restrict__ k, const float* __restrict__ vt,
    const float* __restrict__ gamma_nl_p,
    __hip_bfloat16* __restrict__ ctxh, __hip_bfloat16* __restrict__ ctxl)
{
    int n = blockIdx.x;
    int i0 = blockIdx.y * 128;
    int c0 = blockIdx.z * 128;
    int si = n >> 5, sj = (n >> 4) & 1, b = n & 15;

    __shared__ float Qs[128][8];
    __shared__ float Ks[32][8];
    __shared__ float Ps[128][33];
    __shared__ float Vs[32][132];
    __shared__ float rowmax[128], rowsum[128], rowscale[128];

    int t = threadIdx.x;
    int sg = t & 15, cg = t >> 4;

    for (int idx = t; idx < 128 * 8; idx += 256) {
        int d = idx >> 7, ii = idx & 127;
        Qs[ii][d] = q[((size_t)n * 8 + d) * L_ + i0 + ii];
    }
    if (t < 128) { rowmax[t] = -1e30f; rowsum[t] = 0.f; }
    __syncthreads();

    float qv[8][8];
    #pragma unroll
    for (int r = 0; r < 8; r++)
        #pragma unroll
        for (int d = 0; d < 8; d++) qv[r][d] = Qs[sg * 8 + r][d];

    float acc[8][8] = {};

    for (int j0 = 0; j0 < L_; j0 += 32) {
        {
            int d = t >> 5, jj = t & 31;
            Ks[jj][d] = k[((size_t)n * 8 + d) * L_ + j0 + jj];
        }
        for (int idx = t; idx < 32 * 128; idx += 256) {
            int jj = idx >> 7, cc = idx & 127;
            Vs[jj][cc] = vt[((size_t)n * L_ + j0 + jj) * C_ + c0 + cc];
        }
        __syncthreads();

        #pragma unroll
        for (int jc = 0; jc < 2; jc++) {
            int jj = cg * 2 + jc;
            float kv[8];
            #pragma unroll
            for (int d = 0; d < 8; d++) kv[d] = Ks[jj][d];
            #pragma unroll
            for (int r = 0; r < 8; r++) {
                float s = 0.f;
                #pragma unroll
                for (int d = 0; d < 8; d++) s += qv[r][d] * kv[d];
                Ps[sg * 8 + r][jj] = s;
            }
        }
        __syncthreads();

        if (t < 128) {
            float m = rowmax[t], mx = m;
            float sv[32];
            #pragma unroll
            for (int j = 0; j < 32; j++) { sv[j] = Ps[t][j]; mx = fmaxf(mx, sv[j]); }
            float scale = __expf(m - mx);
            float ssum = 0.f;
            #pragma unroll
            for (int j = 0; j < 32; j++) {
                float p = __expf(sv[j] - mx);
                Ps[t][j] = p;
                ssum += p;
            }
            rowsum[t] = rowsum[t] * scale + ssum;
            rowmax[t] = mx;
            rowscale[t] = scale;
        }
        __syncthreads();

        float sc[8];
        #pragma unroll
        for (int r = 0; r < 8; r++) sc[r] = rowscale[sg * 8 + r];
        #pragma unroll
        for (int r = 0; r < 8; r++)
            #pragma unroll
            for (int j = 0; j < 8; j++) acc[r][j] *= sc[r];
        #pragma unroll 2
        for (int jj = 0; jj < 32; jj++) {
            float pv[8], vv[8];
            #pragma unroll
            for (int r = 0; r < 8; r++) pv[r] = Ps[sg * 8 + r][jj];
            #pragma unroll
            for (int j = 0; j < 8; j++) vv[j] = Vs[jj][cg * 8 + j];
            #pragma unroll
            for (int r = 0; r < 8; r++)
                #pragma unroll
                for (int j = 0; j < 8; j++) acc[r][j] += pv[r] * vv[j];
        }
        __syncthreads();
    }

    float g = gamma_nl_p[0];
    #pragma unroll
    for (int r = 0; r < 8; r++) {
        int i = i0 + sg * 8 + r;
        float rl = 1.0f / rowsum[sg * 8 + r];
        int h = si * 32 + (i >> 5), w = sj * 32 + (i & 31);
        __hip_bfloat16 hb[8], lb[8];
        #pragma unroll
        for (int j = 0; j < 8; j++) {
            int c = c0 + cg * 8 + j;
            size_t xi = ((size_t)(b * C_ + c)) * (H_ * W_) + (size_t)h * W_ + w;
            float v = g * (acc[r][j] * rl) + x[xi];
            hb[j] = __float2bfloat16(v);
            lb[j] = __float2bfloat16(v - __bfloat162float(hb[j]));
        }
        size_t ci = (((size_t)b * H_ + h) * W_ + w) * C_ + c0 + cg * 8;
        *reinterpret_cast<uint4*>(&ctxh[ci]) = *reinterpret_cast<uint4*>(hb);
        *reinterpret_cast<uint4*>(&ctxl[ci]) = *reinterpret_cast<uint4*>(lb);
    }
}

// ---------------------------------------------------------------------------
// Kernel 4a: weight prep — split convW into bf16 hi/lo, pre-swizzled into the
// exact per-lane MFMA B-fragment order:
//   WB[(((tap*8+q)*16+cf)*64+l)*8+j]  holds  B[k][co] with
//   co = cf*16 + (l&15),  ci = q*32 + (l>>4)*8 + j,  tap = kh*3+kw
// ---------------------------------------------------------------------------
__global__ __launch_bounds__(256) void wprep(
    const float* __restrict__ convW,
    __hip_bfloat16* __restrict__ WBh, __hip_bfloat16* __restrict__ WBl)
{
    int e = blockIdx.x * 256 + threadIdx.x;   // < 9*8*16*64*8 = 589824
    int j  = e & 7;
    int l  = (e >> 3) & 63;
    int cf = (e >> 9) & 15;
    int q  = (e >> 13) & 7;
    int tap = e >> 16;
    int co = cf * 16 + (l & 15);
    int ci = q * 32 + (l >> 4) * 8 + j;
    float v = convW[((size_t)co * C_ + ci) * 9 + tap];
    __hip_bfloat16 hi = __float2bfloat16(v);
    __hip_bfloat16 lo = __float2bfloat16(v - __bfloat162float(hi));
    WBh[e] = hi;
    WBl[e] = lo;
}

// ---------------------------------------------------------------------------
// Kernel 4b: 3x3 conv via bf16-split MFMA + BN + gamma residual + ReLU
// block: (b, h-pair).  M=128 px (2 rows x 64 w), N=256 co (64/wave), K=2304.
// grid 512 x 256 threads (4 waves).
// ---------------------------------------------------------------------------
__global__ __launch_bounds__(256, 2) void conv_mfma(
    const __hip_bfloat16* __restrict__ ctxh, const __hip_bfloat16* __restrict__ ctxl,
    const __hip_bfloat16* __restrict__ WBh, const __hip_bfloat16* __restrict__ WBl,
    const float* __restrict__ convb, const float* __restrict__ bn_w,
    const float* __restrict__ bn_b, const float* __restrict__ bn_mean,
    const float* __restrict__ bn_var, const float* __restrict__ gamma_p,
    const float* __restrict__ x, float* __restrict__ out)
{
    // LDS: [plane][hh(4)][wslot(66)][kgp(4)][16B], kg XOR-swizzled by (wslot>>1)&3
    __shared__ __align__(16) char Cs[2 * 1056 * 16];   // 33792 B
    int t = threadIdx.x;
    int l = t & 63, wv = t >> 6;
    int lrow = l & 15, lkg = l >> 4;
    int b = blockIdx.x >> 5;
    int h0 = (blockIdx.x & 31) * 2;

    float gmm = gamma_p[0];
    float sA[4], sB[4];
    #pragma unroll
    for (int f = 0; f < 4; f++) {
        int co = wv * 64 + f * 16 + lrow;
        float inv = bn_w[co] * rsqrtf(bn_var[co] + 1e-5f);
        sA[f] = gmm * inv;
        sB[f] = gmm * ((convb[co] - bn_mean[co]) * inv + bn_b[co]);
    }

    f32x4 acc[8][4];
    #pragma unroll
    for (int mf = 0; mf < 8; mf++)
        #pragma unroll
        for (int f = 0; f < 4; f++) acc[mf][f] = f32x4{0.f, 0.f, 0.f, 0.f};

    for (int q = 0; q < 8; q++) {
        int ci0 = q * 32;
        __syncthreads();
        // stage ctx tile: 4 rows x 66 wslots x 32 ci, hi+lo
        for (int idx = t; idx < 2112; idx += 256) {
            int plane = (idx >= 1056) ? 1 : 0;
            int c2 = plane ? idx - 1056 : idx;
            int kgp = c2 & 3;
            int rem = c2 >> 2;                 // hh*66 + wslot
            int wslot = rem % 66, hh = rem / 66;
            int h = h0 - 1 + hh, w = wslot - 1;
            int kg = kgp ^ ((wslot >> 1) & 3);
            uint4 v = uint4{0u, 0u, 0u, 0u};
            if ((unsigned)h < 64u && (unsigned)w < 64u) {
                const __hip_bfloat16* src = (plane ? ctxl : ctxh)
                    + ((((size_t)b * H_ + h) * W_ + w) * C_ + ci0 + kg * 8);
                v = *reinterpret_cast<const uint4*>(src);
            }
            *reinterpret_cast<uint4*>(&Cs[(plane * 1056 + rem * 4 + kgp) * 16]) = v;
        }
        __syncthreads();

        #pragma unroll
        for (int tap = 0; tap < 9; tap++) {
            const int kh = tap / 3, kw = tap % 3;
            bf16x8 bh[4], bl[4];
            #pragma unroll
            for (int f = 0; f < 4; f++) {
                size_t base = ((((size_t)tap * 8 + q) * 16 + (wv * 4 + f)) * 64 + l) * 8;
                bh[f] = *reinterpret_cast<const bf16x8*>(WBh + base);
                bl[f] = *reinterpret_cast<const bf16x8*>(WBl + base);
            }
            #pragma unroll
            for (int mf = 0; mf < 8; mf++) {
                int wsl = (mf & 3) * 16 + lrow + kw;      // 0..65
                int hh = (mf >> 2) + kh;                   // 0..3
                int kgp = lkg ^ ((wsl >> 1) & 3);
                int off = ((hh * 66 + wsl) * 4 + kgp) * 16;
                bf16x8 ah = *reinterpret_cast<const bf16x8*>(&Cs[off]);
                bf16x8 al = *reinterpret_cast<const bf16x8*>(&Cs[16896 + off]);
                #pragma unroll
                for (int f = 0; f < 4; f++) {
                    acc[mf][f] = __builtin_amdgcn_mfma_f32_16x16x32_bf16(ah, bh[f], acc[mf][f], 0, 0, 0);
                    acc[mf][f] = __builtin_amdgcn_mfma_f32_16x16x32_bf16(ah, bl[f], acc[mf][f], 0, 0, 0);
                    acc[mf][f] = __builtin_amdgcn_mfma_f32_16x16x32_bf16(al, bh[f], acc[mf][f], 0, 0, 0);
                }
            }
        }
    }

    // epilogue: C/D row=(lane>>4)*4+reg -> 4 consecutive w per lane -> float4
    #pragma unroll
    for (int mf = 0; mf < 8; mf++) {
        int h = h0 + (mf >> 2);
        int wb = (mf & 3) * 16 + lkg * 4;
        #pragma unroll
        for (int f = 0; f < 4; f++) {
            int co = wv * 64 + f * 16 + lrow;
            size_t adr = (((size_t)b * C_ + co) * H_ + h) * W_ + wb;
            float4 xr = *reinterpret_cast<const float4*>(x + adr);
            float4 o;
            o.x = fmaxf(sA[f] * acc[mf][f][0] + sB[f] + xr.x, 0.f);
            o.y = fmaxf(sA[f] * acc[mf][f][1] + sB[f] + xr.y, 0.f);
            o.z = fmaxf(sA[f] * acc[mf][f][2] + sB[f] + xr.z, 0.f);
            o.w = fmaxf(sA[f] * acc[mf][f][3] + sB[f] + xr.w, 0.f);
            *reinterpret_cast<float4*>(out + adr) = o;
        }
    }
}

// ---------------------------------------------------------------------------
extern "C" void kernel_launch(void* const* d_in, const int* in_sizes, int n_in,
                              void* d_out, int out_size, void* d_ws, size_t ws_size,
                              hipStream_t stream)
{
    const float* x        = (const float*)d_in[0];
    const float* Wq       = (const float*)d_in[1];
    const float* bq       = (const float*)d_in[2];
    const float* Wk       = (const float*)d_in[3];
    const float* bk       = (const float*)d_in[4];
    const float* Wv       = (const float*)d_in[5];
    const float* bv       = (const float*)d_in[6];
    const float* gamma_nl = (const float*)d_in[7];
    const float* convW    = (const float*)d_in[8];
    const float* convb    = (const float*)d_in[9];
    const float* bn_w     = (const float*)d_in[10];
    const float* bn_b     = (const float*)d_in[11];
    const float* bn_mean  = (const float*)d_in[12];
    const float* bn_var   = (const float*)d_in[13];
    const float* gamma    = (const float*)d_in[14];
    float* out = (float*)d_out;

    // workspace layout (floats then bf16 planes)
    float* q   = (float*)d_ws;                          // 524288 f32
    float* k   = q  + (size_t)N_ * 8 * L_;              // 524288 f32
    float* vt  = k  + (size_t)N_ * 8 * L_;              // 16777216 f32
    __hip_bfloat16* ctxh = (__hip_bfloat16*)(vt + (size_t)N_ * L_ * C_);
    __hip_bfloat16* ctxl = ctxh + (size_t)B_ * C_ * H_ * W_;
    __hip_bfloat16* WBh  = ctxl + (size_t)B_ * C_ * H_ * W_;
    __hip_bfloat16* WBl  = WBh + (size_t)9 * 8 * 16 * 64 * 8;

    wprep<<<dim3(589824 / 256), dim3(256), 0, stream>>>(convW, WBh, WBl);
    qk_proj<<<dim3(N_ * L_ / 256), dim3(256), 0, stream>>>(x, Wq, bq, Wk, bk, q, k);
    v_proj<<<dim3(N_, 8, 2), dim3(256), 0, stream>>>(x, Wv, bv, vt);
    attn_kernel<<<dim3(N_, 8, 2), dim3(256), 0, stream>>>(x, q, k, vt, gamma_nl, ctxh, ctxl);
    conv_mfma<<<dim3(512), dim3(256), 0, stream>>>(
        ctxh, ctxl, WBh, WBl, convb, bn_w, bn_b, bn_mean, bn_var, gamma, x, out);
}

// Round 3
// 810.140 us; speedup vs baseline: 1.5179x; 1.5179x over previous
//
#include <hip/hip_runtime.h>
#include <hip/hip_bf16.h>
#include <math.h>

#define B_   16
#define C_   256
#define H_   64
#define W_   64
#define L_   1024   // 32*32 per quadrant
#define N_   64     // s*s*B
#define D_   8      // inter channels for q/k

typedef short bf16x8 __attribute__((ext_vector_type(8)));
typedef float f32x4  __attribute__((ext_vector_type(4)));

static __device__ __forceinline__ unsigned short bf16bits(float v) {
    __hip_bfloat16 h = __float2bfloat16(v);
    return *reinterpret_cast<unsigned short*>(&h);
}

// ---------------------------------------------------------------------------
// Kernel 1: q/k projection.  q,k [N,8,L] = W[8,256] @ xb[N,256,L] + b
// ---------------------------------------------------------------------------
__global__ __launch_bounds__(256) void qk_proj(
    const float* __restrict__ x, const float* __restrict__ Wq,
    const float* __restrict__ bq, const float* __restrict__ Wk,
    const float* __restrict__ bk, float* __restrict__ q, float* __restrict__ k)
{
    __shared__ float Ws[16][C_];
    __shared__ float bs[16];
    int t = threadIdx.x;
    for (int i = t; i < 8 * C_; i += 256) {
        Ws[i >> 8][i & 255]       = Wq[i];
        Ws[8 + (i >> 8)][i & 255] = Wk[i];
    }
    if (t < 8) { bs[t] = bq[t]; bs[8 + t] = bk[t]; }
    __syncthreads();

    int gid = blockIdx.x * 256 + t;
    int n = gid >> 10, l = gid & 1023;
    int si = n >> 5, sj = (n >> 4) & 1, b = n & 15;
    int h = si * 32 + (l >> 5), w = sj * 32 + (l & 31);
    const float* xp = x + ((size_t)(b * C_) * H_ + h) * W_ + w;

    float acc[16];
    #pragma unroll
    for (int d = 0; d < 16; d++) acc[d] = bs[d];

    for (int c0 = 0; c0 < C_; c0 += 4) {
        float xv[4];
        #pragma unroll
        for (int u = 0; u < 4; u++) xv[u] = xp[(size_t)(c0 + u) * (H_ * W_)];
        #pragma unroll
        for (int d = 0; d < 16; d++) {
            float4 wv = *reinterpret_cast<const float4*>(&Ws[d][c0]);
            acc[d] += wv.x * xv[0] + wv.y * xv[1] + wv.z * xv[2] + wv.w * xv[3];
        }
    }
    #pragma unroll
    for (int d = 0; d < 8; d++) q[((size_t)n * 8 + d) * L_ + l] = acc[d];
    #pragma unroll
    for (int d = 0; d < 8; d++) k[((size_t)n * 8 + d) * L_ + l] = acc[8 + d];
}

// ---------------------------------------------------------------------------
// Kernel 2: v projection GEMM (fp32) -> vtT hi/lo bf16, layout [n][c][j]
// ---------------------------------------------------------------------------
__global__ __launch_bounds__(256) void v_proj(
    const float* __restrict__ x, const float* __restrict__ Wv,
    const float* __restrict__ bv,
    __hip_bfloat16* __restrict__ vth, __hip_bfloat16* __restrict__ vtl)
{
    int n = blockIdx.x;
    int l0 = blockIdx.y * 128;
    int c0 = blockIdx.z * 128;
    int si = n >> 5, sj = (n >> 4) & 1, b = n & 15;
    __shared__ float Xs[16][132];
    __shared__ float Ws[16][132];
    int t = threadIdx.x;
    int lr = t & 15, cr = t >> 4;
    float acc[8][8] = {};
    const size_t HW = (size_t)H_ * W_;

    for (int k0 = 0; k0 < C_; k0 += 16) {
        for (int idx = t; idx < 16 * 128; idx += 256) {
            int kk = idx >> 7, ll = idx & 127;
            int l = l0 + ll;
            int h = si * 32 + (l >> 5), w = sj * 32 + (l & 31);
            Xs[kk][ll] = x[((size_t)(b * C_ + k0 + kk)) * HW + h * W_ + w];
        }
        for (int idx = t; idx < 16 * 128; idx += 256) {
            int cc = idx >> 4, kk = idx & 15;
            Ws[kk][cc] = Wv[(size_t)(c0 + cc) * C_ + k0 + kk];
        }
        __syncthreads();
        #pragma unroll 4
        for (int kk = 0; kk < 16; kk++) {
            float a[8], bb[8];
            #pragma unroll
            for (int r = 0; r < 8; r++) a[r] = Xs[kk][lr * 8 + r];
            #pragma unroll
            for (int j = 0; j < 8; j++) bb[j] = Ws[kk][cr * 8 + j];
            #pragma unroll
            for (int r = 0; r < 8; r++)
                #pragma unroll
                for (int j = 0; j < 8; j++) acc[r][j] += a[r] * bb[j];
        }
        __syncthreads();
    }
    // epilogue: per c, 8 consecutive l -> bf16x8 hi/lo, layout [n][c][1024]
    #pragma unroll
    for (int j = 0; j < 8; j++) {
        int c = c0 + cr * 8 + j;
        float bias = bv[c];
        unsigned short hb[8], lb[8];
        #pragma unroll
        for (int r = 0; r < 8; r++) {
            float v = acc[r][j] + bias;
            unsigned short h = bf16bits(v);
            hb[r] = h;
            __hip_bfloat16 hh = *reinterpret_cast<__hip_bfloat16*>(&h);
            lb[r] = bf16bits(v - __bfloat162float(hh));
        }
        size_t base = ((size_t)n * C_ + c) * L_ + l0 + lr * 8;
        *reinterpret_cast<uint4*>(vth + base) = *reinterpret_cast<uint4*>(hb);
        *reinterpret_cast<uint4*>(vtl + base) = *reinterpret_cast<uint4*>(lb);
    }
}

// ---------------------------------------------------------------------------
// Kernel 3: attention with MFMA PV (hi/lo split), online softmax.
// block = (n, 64-row i-tile); 4 waves, wave w owns channels w*64..+63.
// grid 1024: bid = ((n&7)*16 + it)*8 + (n>>3)  (XCD-grouped by n)
// ---------------------------------------------------------------------------
__global__ __launch_bounds__(256) void attn_mfma(
    const float* __restrict__ x, const float* __restrict__ q,
    const float* __restrict__ k,
    const __hip_bfloat16* __restrict__ vth, const __hip_bfloat16* __restrict__ vtl,
    const float* __restrict__ gamma_nl_p,
    __hip_bfloat16* __restrict__ ctxh, __hip_bfloat16* __restrict__ ctxl)
{
    int bid = blockIdx.x;
    int xcd = bid & 7, rr = bid >> 3;
    int n = (xcd << 3) | (rr >> 4);
    int it = rr & 15;
    int i0 = it * 64;
    int si = n >> 5, sj = (n >> 4) & 1, b = n & 15;

    __shared__ __align__(16) char Ph[64 * 128];   // [row][jg 16B, XOR-swizzled]
    __shared__ __align__(16) char Pl[64 * 128];
    __shared__ float Kt[2][8][64];
    __shared__ float scl[64];
    __shared__ float sums[64];

    int t = threadIdx.x;
    int l = t & 63, wv = t >> 6;
    int lane16 = l & 15, lkg = l >> 4;

    // S-compute mapping: 4 threads per row, 16 j's each
    int srow = wv * 16 + (l >> 2);
    int sj4 = l & 3;

    float qr[8];
    #pragma unroll
    for (int d = 0; d < 8; d++)
        qr[d] = q[((size_t)n * 8 + d) * L_ + i0 + srow];

    // stage Kt[0]
    #pragma unroll
    for (int u = 0; u < 2; u++) {
        int e = t + u * 256;
        int d = e >> 6, j = e & 63;
        Kt[0][d][j] = k[((size_t)n * 8 + d) * L_ + j];
    }

    float m = -1e30f, psum = 0.f;
    f32x4 acc[4][4];
    #pragma unroll
    for (int mf = 0; mf < 4; mf++)
        #pragma unroll
        for (int f = 0; f < 4; f++) acc[mf][f] = f32x4{0.f, 0.f, 0.f, 0.f};

    for (int tile = 0; tile < 16; tile++) {
        __syncthreads();                       // B1: P consumed, Kt[tile] ready
        int buf = tile & 1;

        // S = Q K^T : 16 values per thread
        float s[16];
        #pragma unroll
        for (int jj = 0; jj < 16; jj++) s[jj] = 0.f;
        #pragma unroll
        for (int d = 0; d < 8; d++) {
            const float* kp = &Kt[buf][d][sj4 * 16];
            float kv[16];
            *reinterpret_cast<float4*>(&kv[0])  = *reinterpret_cast<const float4*>(kp);
            *reinterpret_cast<float4*>(&kv[4])  = *reinterpret_cast<const float4*>(kp + 4);
            *reinterpret_cast<float4*>(&kv[8])  = *reinterpret_cast<const float4*>(kp + 8);
            *reinterpret_cast<float4*>(&kv[12]) = *reinterpret_cast<const float4*>(kp + 12);
            float qd = qr[d];
            #pragma unroll
            for (int jj = 0; jj < 16; jj++) s[jj] += qd * kv[jj];
        }

        // online softmax (per-row, replicated across the 4 quad threads)
        float pmax = s[0];
        #pragma unroll
        for (int jj = 1; jj < 16; jj++) pmax = fmaxf(pmax, s[jj]);
        pmax = fmaxf(pmax, __shfl_xor(pmax, 1));
        pmax = fmaxf(pmax, __shfl_xor(pmax, 2));
        float mnew = fmaxf(m, pmax);
        float sc = __expf(m - mnew);
        m = mnew;
        psum *= sc;
        float p[16];
        #pragma unroll
        for (int jj = 0; jj < 16; jj++) {
            p[jj] = __expf(s[jj] - m);
            psum += p[jj];
        }
        if ((l & 3) == 0) scl[srow] = sc;

        // convert P to hi/lo bf16, store to swizzled LDS (A-frag layout)
        #pragma unroll
        for (int g = 0; g < 2; g++) {
            unsigned short hb[8], lb[8];
            #pragma unroll
            for (int u = 0; u < 8; u++) {
                float pv = p[g * 8 + u];
                unsigned short h = bf16bits(pv);
                hb[u] = h;
                __hip_bfloat16 hh = *reinterpret_cast<__hip_bfloat16*>(&h);
                lb[u] = bf16bits(pv - __bfloat162float(hh));
            }
            int jg = sj4 * 2 + g;
            int off = srow * 128 + ((jg ^ (srow & 7)) << 4);
            *reinterpret_cast<uint4*>(&Ph[off]) = *reinterpret_cast<uint4*>(hb);
            *reinterpret_cast<uint4*>(&Pl[off]) = *reinterpret_cast<uint4*>(lb);
        }
        __syncthreads();                       // B2: P + scl visible

        // rescale accumulator (unconditional; scl==1 for non-rescale rows... always exact)
        #pragma unroll
        for (int mf = 0; mf < 4; mf++) {
            #pragma unroll
            for (int e = 0; e < 4; e++) {
                float se = scl[mf * 16 + lkg * 4 + e];
                #pragma unroll
                for (int f = 0; f < 4; f++) acc[mf][f][e] *= se;
            }
        }

        // stage next Kt (overlaps MFMA below)
        if (tile < 15) {
            #pragma unroll
            for (int u = 0; u < 2; u++) {
                int e = t + u * 256;
                int d = e >> 6, j = e & 63;
                Kt[buf ^ 1][d][j] = k[((size_t)n * 8 + d) * L_ + (tile + 1) * 64 + j];
            }
        }

        // PV: 2 k-steps of 32, 3-term hi/lo split
        int j0 = tile * 64;
        #pragma unroll
        for (int ks = 0; ks < 2; ks++) {
            bf16x8 bh[4], bl[4];
            #pragma unroll
            for (int f = 0; f < 4; f++) {
                size_t vbase = ((size_t)n * C_ + wv * 64 + f * 16 + lane16) * L_
                             + j0 + ks * 32 + lkg * 8;
                bh[f] = *reinterpret_cast<const bf16x8*>(vth + vbase);
                bl[f] = *reinterpret_cast<const bf16x8*>(vtl + vbase);
            }
            #pragma unroll
            for (int mf = 0; mf < 4; mf++) {
                int row = mf * 16 + lane16;
                int off = row * 128 + (((ks * 4 + lkg) ^ (row & 7)) << 4);
                bf16x8 ah = *reinterpret_cast<const bf16x8*>(&Ph[off]);
                bf16x8 al = *reinterpret_cast<const bf16x8*>(&Pl[off]);
                #pragma unroll
                for (int f = 0; f < 4; f++) {
                    acc[mf][f] = __builtin_amdgcn_mfma_f32_16x16x32_bf16(ah, bh[f], acc[mf][f], 0, 0, 0);
                    acc[mf][f] = __builtin_amdgcn_mfma_f32_16x16x32_bf16(al, bh[f], acc[mf][f], 0, 0, 0);
                    acc[mf][f] = __builtin_amdgcn_mfma_f32_16x16x32_bf16(ah, bl[f], acc[mf][f], 0, 0, 0);
                }
            }
        }
    }

    // row sums: reduce across the 4 quad threads
    psum += __shfl_xor(psum, 1);
    psum += __shfl_xor(psum, 2);
    if ((l & 3) == 0) sums[srow] = psum;
    __syncthreads();

    float g = gamma_nl_p[0];
    #pragma unroll
    for (int mf = 0; mf < 4; mf++) {
        #pragma unroll
        for (int e = 0; e < 4; e++) {
            int i = i0 + mf * 16 + lkg * 4 + e;
            float rs = 1.0f / sums[mf * 16 + lkg * 4 + e];
            int h = si * 32 + (i >> 5), w = sj * 32 + (i & 31);
            #pragma unroll
            for (int f = 0; f < 4; f++) {
                int c = wv * 64 + f * 16 + lane16;
                float xv = x[((size_t)(b * C_ + c)) * (H_ * W_) + (size_t)h * W_ + w];
                float o = g * (acc[mf][f][e] * rs) + xv;
                unsigned short hbits = bf16bits(o);
                __hip_bfloat16 hh = *reinterpret_cast<__hip_bfloat16*>(&hbits);
                unsigned short lbits = bf16bits(o - __bfloat162float(hh));
                size_t ci = (((size_t)b * H_ + h) * W_ + w) * C_ + c;
                *reinterpret_cast<unsigned short*>(&ctxh[ci]) = hbits;
                *reinterpret_cast<unsigned short*>(&ctxl[ci]) = lbits;
            }
        }
    }
}

// ---------------------------------------------------------------------------
// Kernel 4a: conv weight prep (unchanged)
// ---------------------------------------------------------------------------
__global__ __launch_bounds__(256) void wprep(
    const float* __restrict__ convW,
    __hip_bfloat16* __restrict__ WBh, __hip_bfloat16* __restrict__ WBl)
{
    int e = blockIdx.x * 256 + threadIdx.x;   // < 9*8*16*64*8 = 589824
    int j  = e & 7;
    int l  = (e >> 3) & 63;
    int cf = (e >> 9) & 15;
    int q  = (e >> 13) & 7;
    int tap = e >> 16;
    int co = cf * 16 + (l & 15);
    int ci = q * 32 + (l >> 4) * 8 + j;
    float v = convW[((size_t)co * C_ + ci) * 9 + tap];
    __hip_bfloat16 hi = __float2bfloat16(v);
    __hip_bfloat16 lo = __float2bfloat16(v - __bfloat162float(hi));
    WBh[e] = hi;
    WBl[e] = lo;
}

// ---------------------------------------------------------------------------
// Kernel 4b: 3x3 conv via bf16-split MFMA + BN + gamma residual + ReLU
// (unchanged from round 1)
// ---------------------------------------------------------------------------
__global__ __launch_bounds__(256, 2) void conv_mfma(
    const __hip_bfloat16* __restrict__ ctxh, const __hip_bfloat16* __restrict__ ctxl,
    const __hip_bfloat16* __restrict__ WBh, const __hip_bfloat16* __restrict__ WBl,
    const float* __restrict__ convb, const float* __restrict__ bn_w,
    const float* __restrict__ bn_b, const float* __restrict__ bn_mean,
    const float* __restrict__ bn_var, const float* __restrict__ gamma_p,
    const float* __restrict__ x, float* __restrict__ out)
{
    __shared__ __align__(16) char Cs[2 * 1056 * 16];   // 33792 B
    int t = threadIdx.x;
    int l = t & 63, wv = t >> 6;
    int lrow = l & 15, lkg = l >> 4;
    int b = blockIdx.x >> 5;
    int h0 = (blockIdx.x & 31) * 2;

    float gmm = gamma_p[0];
    float sA[4], sB[4];
    #pragma unroll
    for (int f = 0; f < 4; f++) {
        int co = wv * 64 + f * 16 + lrow;
        float inv = bn_w[co] * rsqrtf(bn_var[co] + 1e-5f);
        sA[f] = gmm * inv;
        sB[f] = gmm * ((convb[co] - bn_mean[co]) * inv + bn_b[co]);
    }

    f32x4 acc[8][4];
    #pragma unroll
    for (int mf = 0; mf < 8; mf++)
        #pragma unroll
        for (int f = 0; f < 4; f++) acc[mf][f] = f32x4{0.f, 0.f, 0.f, 0.f};

    for (int q = 0; q < 8; q++) {
        int ci0 = q * 32;
        __syncthreads();
        for (int idx = t; idx < 2112; idx += 256) {
            int plane = (idx >= 1056) ? 1 : 0;
            int c2 = plane ? idx - 1056 : idx;
            int kgp = c2 & 3;
            int rem = c2 >> 2;
            int wslot = rem % 66, hh = rem / 66;
            int h = h0 - 1 + hh, w = wslot - 1;
            int kg = kgp ^ ((wslot >> 1) & 3);
            uint4 v = uint4{0u, 0u, 0u, 0u};
            if ((unsigned)h < 64u && (unsigned)w < 64u) {
                const __hip_bfloat16* src = (plane ? ctxl : ctxh)
                    + ((((size_t)b * H_ + h) * W_ + w) * C_ + ci0 + kg * 8);
                v = *reinterpret_cast<const uint4*>(src);
            }
            *reinterpret_cast<uint4*>(&Cs[(plane * 1056 + rem * 4 + kgp) * 16]) = v;
        }
        __syncthreads();

        #pragma unroll
        for (int tap = 0; tap < 9; tap++) {
            const int kh = tap / 3, kw = tap % 3;
            bf16x8 bh[4], bl[4];
            #pragma unroll
            for (int f = 0; f < 4; f++) {
                size_t base = ((((size_t)tap * 8 + q) * 16 + (wv * 4 + f)) * 64 + l) * 8;
                bh[f] = *reinterpret_cast<const bf16x8*>(WBh + base);
                bl[f] = *reinterpret_cast<const bf16x8*>(WBl + base);
            }
            #pragma unroll
            for (int mf = 0; mf < 8; mf++) {
                int wsl = (mf & 3) * 16 + lrow + kw;
                int hh = (mf >> 2) + kh;
                int kgp = lkg ^ ((wsl >> 1) & 3);
                int off = ((hh * 66 + wsl) * 4 + kgp) * 16;
                bf16x8 ah = *reinterpret_cast<const bf16x8*>(&Cs[off]);
                bf16x8 al = *reinterpret_cast<const bf16x8*>(&Cs[16896 + off]);
                #pragma unroll
                for (int f = 0; f < 4; f++) {
                    acc[mf][f] = __builtin_amdgcn_mfma_f32_16x16x32_bf16(ah, bh[f], acc[mf][f], 0, 0, 0);
                    acc[mf][f] = __builtin_amdgcn_mfma_f32_16x16x32_bf16(ah, bl[f], acc[mf][f], 0, 0, 0);
                    acc[mf][f] = __builtin_amdgcn_mfma_f32_16x16x32_bf16(al, bh[f], acc[mf][f], 0, 0, 0);
                }
            }
        }
    }

    #pragma unroll
    for (int mf = 0; mf < 8; mf++) {
        int h = h0 + (mf >> 2);
        int wb = (mf & 3) * 16 + lkg * 4;
        #pragma unroll
        for (int f = 0; f < 4; f++) {
            int co = wv * 64 + f * 16 + lrow;
            size_t adr = (((size_t)b * C_ + co) * H_ + h) * W_ + wb;
            float4 xr = *reinterpret_cast<const float4*>(x + adr);
            float4 o;
            o.x = fmaxf(sA[f] * acc[mf][f][0] + sB[f] + xr.x, 0.f);
            o.y = fmaxf(sA[f] * acc[mf][f][1] + sB[f] + xr.y, 0.f);
            o.z = fmaxf(sA[f] * acc[mf][f][2] + sB[f] + xr.z, 0.f);
            o.w = fmaxf(sA[f] * acc[mf][f][3] + sB[f] + xr.w, 0.f);
            *reinterpret_cast<float4*>(out + adr) = o;
        }
    }
}

// ---------------------------------------------------------------------------
extern "C" void kernel_launch(void* const* d_in, const int* in_sizes, int n_in,
                              void* d_out, int out_size, void* d_ws, size_t ws_size,
                              hipStream_t stream)
{
    const float* x        = (const float*)d_in[0];
    const float* Wq       = (const float*)d_in[1];
    const float* bq       = (const float*)d_in[2];
    const float* Wk       = (const float*)d_in[3];
    const float* bk       = (const float*)d_in[4];
    const float* Wv       = (const float*)d_in[5];
    const float* bv       = (const float*)d_in[6];
    const float* gamma_nl = (const float*)d_in[7];
    const float* convW    = (const float*)d_in[8];
    const float* convb    = (const float*)d_in[9];
    const float* bn_w     = (const float*)d_in[10];
    const float* bn_b     = (const float*)d_in[11];
    const float* bn_mean  = (const float*)d_in[12];
    const float* bn_var   = (const float*)d_in[13];
    const float* gamma    = (const float*)d_in[14];
    float* out = (float*)d_out;

    float* q   = (float*)d_ws;                           // 524288 f32
    float* k   = q  + (size_t)N_ * 8 * L_;               // 524288 f32
    __hip_bfloat16* vth  = (__hip_bfloat16*)(k + (size_t)N_ * 8 * L_);
    __hip_bfloat16* vtl  = vth + (size_t)N_ * C_ * L_;   // 16.78M each
    __hip_bfloat16* ctxh = vtl + (size_t)N_ * C_ * L_;
    __hip_bfloat16* ctxl = ctxh + (size_t)B_ * C_ * H_ * W_;
    __hip_bfloat16* WBh  = ctxl + (size_t)B_ * C_ * H_ * W_;
    __hip_bfloat16* WBl  = WBh + (size_t)9 * 8 * 16 * 64 * 8;

    wprep<<<dim3(589824 / 256), dim3(256), 0, stream>>>(convW, WBh, WBl);
    qk_proj<<<dim3(N_ * L_ / 256), dim3(256), 0, stream>>>(x, Wq, bq, Wk, bk, q, k);
    v_proj<<<dim3(N_, 8, 2), dim3(256), 0, stream>>>(x, Wv, bv, vth, vtl);
    attn_mfma<<<dim3(1024), dim3(256), 0, stream>>>(
        x, q, k, vth, vtl, gamma_nl, ctxh, ctxl);
    conv_mfma<<<dim3(512), dim3(256), 0, stream>>>(
        ctxh, ctxl, WBh, WBl, convb, bn_w, bn_b, bn_mean, bn_var, gamma, x, out);
}

// Round 8
// 531.380 us; speedup vs baseline: 2.3142x; 1.5246x over previous
//
#include <hip/hip_runtime.h>
#include <hip/hip_bf16.h>
#include <math.h>

#define B_   16
#define C_   256
#define H_   64
#define W_   64
#define L_   1024   // 32*32 per quadrant
#define N_   64     // s*s*B
#define D_   8      // inter channels for q/k

typedef _Float16 f16x8 __attribute__((ext_vector_type(8)));
typedef float    f32x4 __attribute__((ext_vector_type(4)));

static __device__ __forceinline__ unsigned short f16bits(float v) {
    _Float16 h = (_Float16)v;
    return *reinterpret_cast<unsigned short*>(&h);
}
static __device__ __forceinline__ float f16tof(unsigned short b) {
    _Float16 h = *reinterpret_cast<_Float16*>(&b);
    return (float)h;
}

// ---------------------------------------------------------------------------
// Kernel 1: q/k projection.  q,k [N,8,L] = W[8,256] @ xb[N,256,L] + b
// ---------------------------------------------------------------------------
__global__ __launch_bounds__(256) void qk_proj(
    const float* __restrict__ x, const float* __restrict__ Wq,
    const float* __restrict__ bq, const float* __restrict__ Wk,
    const float* __restrict__ bk, float* __restrict__ q, float* __restrict__ k)
{
    __shared__ float Ws[16][C_];
    __shared__ float bs[16];
    int t = threadIdx.x;
    for (int i = t; i < 8 * C_; i += 256) {
        Ws[i >> 8][i & 255]       = Wq[i];
        Ws[8 + (i >> 8)][i & 255] = Wk[i];
    }
    if (t < 8) { bs[t] = bq[t]; bs[8 + t] = bk[t]; }
    __syncthreads();

    int gid = blockIdx.x * 256 + t;
    int n = gid >> 10, l = gid & 1023;
    int si = n >> 5, sj = (n >> 4) & 1, b = n & 15;
    int h = si * 32 + (l >> 5), w = sj * 32 + (l & 31);
    const float* xp = x + ((size_t)(b * C_) * H_ + h) * W_ + w;

    float acc[16];
    #pragma unroll
    for (int d = 0; d < 16; d++) acc[d] = bs[d];

    for (int c0 = 0; c0 < C_; c0 += 4) {
        float xv[4];
        #pragma unroll
        for (int u = 0; u < 4; u++) xv[u] = xp[(size_t)(c0 + u) * (H_ * W_)];
        #pragma unroll
        for (int d = 0; d < 16; d++) {
            float4 wv = *reinterpret_cast<const float4*>(&Ws[d][c0]);
            acc[d] += wv.x * xv[0] + wv.y * xv[1] + wv.z * xv[2] + wv.w * xv[3];
        }
    }
    #pragma unroll
    for (int d = 0; d < 8; d++) q[((size_t)n * 8 + d) * L_ + l] = acc[d];
    #pragma unroll
    for (int d = 0; d < 8; d++) k[((size_t)n * 8 + d) * L_ + l] = acc[8 + d];
}

// ---------------------------------------------------------------------------
// Kernel 2a: Wv prep — fp16, pre-swizzled B-frag order
//   WV2[((kq*16 + cf)*64 + l)*8 + j] = Wv[c][k], c=cf*16+(l&15), k=kq*32+(l>>4)*8+j
// ---------------------------------------------------------------------------
__global__ __launch_bounds__(256) void wprep2(
    const float* __restrict__ Wv, unsigned short* __restrict__ WV2)
{
    int e = blockIdx.x * 256 + threadIdx.x;   // < 8*16*64*8 = 65536
    int j  = e & 7;
    int l  = (e >> 3) & 63;
    int cf = (e >> 9) & 15;
    int kq = e >> 13;
    int c = cf * 16 + (l & 15);
    int k = kq * 32 + (l >> 4) * 8 + j;
    WV2[e] = f16bits(Wv[(size_t)c * C_ + k]);
}

// ---------------------------------------------------------------------------
// Kernel 2b: v projection via fp16 MFMA -> vt fp16, layout [n][c][l]
// block = (n, 128-l tile); 4 waves; wave wv stages its 32-l slice (lane = k).
// grid 512 x 256.
// ---------------------------------------------------------------------------
__global__ __launch_bounds__(256, 2) void v_proj_mfma(
    const float* __restrict__ x, const unsigned short* __restrict__ WV2,
    const float* __restrict__ bv, unsigned short* __restrict__ vth)
{
    __shared__ __align__(16) unsigned short Xs[128][72];   // [l][k], pad 72
    int bid = blockIdx.x;
    int n = bid >> 3, lt = bid & 7;
    int l0 = lt * 128;
    int si = n >> 5, sj = (n >> 4) & 1, b = n & 15;
    int t = threadIdx.x;
    int lane = t & 63, wv = t >> 6;
    int lane16 = lane & 15, lkg = lane >> 4;

    f32x4 acc[8][4];
    #pragma unroll
    for (int lf = 0; lf < 8; lf++)
        #pragma unroll
        for (int f = 0; f < 4; f++) acc[lf][f] = f32x4{0.f, 0.f, 0.f, 0.f};

    // this wave stages l-rows [wv*32, wv*32+32): h row is fixed
    int hrow = si * 32 + (l0 >> 5) + wv;
    const float* xbase = x + ((size_t)b * C_) * (H_ * W_) + hrow * W_ + sj * 32;

    for (int kc = 0; kc < 4; kc++) {
        __syncthreads();                       // Xs consumed by all waves
        const float* xp = xbase + (size_t)(kc * 64 + lane) * (H_ * W_);
        #pragma unroll
        for (int u4 = 0; u4 < 8; u4++) {
            float4 v = *reinterpret_cast<const float4*>(xp + u4 * 4);
            Xs[wv * 32 + u4 * 4 + 0][lane] = f16bits(v.x);
            Xs[wv * 32 + u4 * 4 + 1][lane] = f16bits(v.y);
            Xs[wv * 32 + u4 * 4 + 2][lane] = f16bits(v.z);
            Xs[wv * 32 + u4 * 4 + 3][lane] = f16bits(v.w);
        }
        __syncthreads();

        #pragma unroll
        for (int ks = 0; ks < 2; ks++) {
            int kq = kc * 2 + ks;
            f16x8 bh[4];
            #pragma unroll
            for (int f = 0; f < 4; f++) {
                size_t base = (((size_t)kq * 16 + (wv * 4 + f)) * 64 + lane) * 8;
                bh[f] = *reinterpret_cast<const f16x8*>(WV2 + base);
            }
            #pragma unroll
            for (int lf = 0; lf < 8; lf++) {
                f16x8 ah = *reinterpret_cast<const f16x8*>(
                    &Xs[lf * 16 + lane16][ks * 32 + lkg * 8]);
                #pragma unroll
                for (int f = 0; f < 4; f++)
                    acc[lf][f] = __builtin_amdgcn_mfma_f32_16x16x32_f16(ah, bh[f], acc[lf][f], 0, 0, 0);
            }
        }
    }

    // epilogue: lane holds 4 consecutive l per (lf,f); c = (wv*4+f)*16 + lane16
    float bias[4];
    #pragma unroll
    for (int f = 0; f < 4; f++) bias[f] = bv[(wv * 4 + f) * 16 + lane16];
    #pragma unroll
    for (int lf = 0; lf < 8; lf++) {
        #pragma unroll
        for (int f = 0; f < 4; f++) {
            int c = (wv * 4 + f) * 16 + lane16;
            unsigned short hb[4];
            #pragma unroll
            for (int e = 0; e < 4; e++)
                hb[e] = f16bits(acc[lf][f][e] + bias[f]);
            size_t base = ((size_t)n * C_ + c) * L_ + l0 + lf * 16 + lkg * 4;
            *reinterpret_cast<uint2*>(vth + base) = *reinterpret_cast<uint2*>(hb);
        }
    }
}

// ---------------------------------------------------------------------------
// Kernel 3: attention, MFMA PV (fp16 P,V), online softmax.
// block = (n, 64-row i-tile); 4 waves, wave w owns channels w*64..+63.
// grid 1024: bid = ((n&7)*16 + it)*8 + (n>>3)  (XCD-grouped by n)
// ---------------------------------------------------------------------------
__global__ __launch_bounds__(256) void attn_mfma(
    const float* __restrict__ x, const float* __restrict__ q,
    const float* __restrict__ k, const unsigned short* __restrict__ vth,
    const float* __restrict__ gamma_nl_p, unsigned short* __restrict__ ctxh)
{
    int bid = blockIdx.x;
    int xcd = bid & 7, rr = bid >> 3;
    int n = (xcd << 3) | (rr >> 4);
    int it = rr & 15;
    int i0 = it * 64;
    int si = n >> 5, sj = (n >> 4) & 1, b = n & 15;

    // smem pool: phase1 = Ph(8192) | Kt(4096) | scl(256); phase2 = 64x264 u16
    __shared__ __align__(16) char smem[64 * 264 * 2];
    __shared__ float sums[64];
    char* Ph = smem;
    float (*Kt)[8][64] = (float (*)[8][64])(smem + 8192);
    float* scl = (float*)(smem + 8192 + 4096);

    int t = threadIdx.x;
    int l = t & 63, wv = t >> 6;
    int lane16 = l & 15, lkg = l >> 4;
    int srow = wv * 16 + (l >> 2);   // S-mapping: 4 threads/row, 16 j each
    int sj4 = l & 3;

    float qr[8];
    #pragma unroll
    for (int d = 0; d < 8; d++)
        qr[d] = q[((size_t)n * 8 + d) * L_ + i0 + srow];

    #pragma unroll
    for (int u = 0; u < 2; u++) {
        int e = t + u * 256;
        int d = e >> 6, j = e & 63;
        Kt[0][d][j] = k[((size_t)n * 8 + d) * L_ + j];
    }

    float m = -1e30f, psum = 0.f;
    f32x4 acc[4][4];
    #pragma unroll
    for (int mf = 0; mf < 4; mf++)
        #pragma unroll
        for (int f = 0; f < 4; f++) acc[mf][f] = f32x4{0.f, 0.f, 0.f, 0.f};

    for (int tile = 0; tile < 16; tile++) {
        __syncthreads();                       // B1: P consumed, Kt[tile] ready
        int buf = tile & 1;

        float s[16];
        #pragma unroll
        for (int jj = 0; jj < 16; jj++) s[jj] = 0.f;
        #pragma unroll
        for (int d = 0; d < 8; d++) {
            const float* kp = &Kt[buf][d][sj4 * 16];
            float kv[16];
            *reinterpret_cast<float4*>(&kv[0])  = *reinterpret_cast<const float4*>(kp);
            *reinterpret_cast<float4*>(&kv[4])  = *reinterpret_cast<const float4*>(kp + 4);
            *reinterpret_cast<float4*>(&kv[8])  = *reinterpret_cast<const float4*>(kp + 8);
            *reinterpret_cast<float4*>(&kv[12]) = *reinterpret_cast<const float4*>(kp + 12);
            float qd = qr[d];
            #pragma unroll
            for (int jj = 0; jj < 16; jj++) s[jj] += qd * kv[jj];
        }

        float pmax = s[0];
        #pragma unroll
        for (int jj = 1; jj < 16; jj++) pmax = fmaxf(pmax, s[jj]);
        pmax = fmaxf(pmax, __shfl_xor(pmax, 1));
        pmax = fmaxf(pmax, __shfl_xor(pmax, 2));
        float mnew = fmaxf(m, pmax);
        float sc = __expf(m - mnew);
        m = mnew;
        psum *= sc;
        float p[16];
        #pragma unroll
        for (int jj = 0; jj < 16; jj++) {
            p[jj] = __expf(s[jj] - m);
            psum += p[jj];
        }
        if ((l & 3) == 0) scl[srow] = sc;

        // P -> fp16, swizzled LDS (A-frag layout)
        #pragma unroll
        for (int g = 0; g < 2; g++) {
            unsigned short hb[8];
            #pragma unroll
            for (int u = 0; u < 8; u++) hb[u] = f16bits(p[g * 8 + u]);
            int jg = sj4 * 2 + g;
            int off = srow * 128 + ((jg ^ (srow & 7)) << 4);
            *reinterpret_cast<uint4*>(&Ph[off]) = *reinterpret_cast<uint4*>(hb);
        }
        __syncthreads();                       // B2: P + scl visible

        #pragma unroll
        for (int mf = 0; mf < 4; mf++) {
            #pragma unroll
            for (int e = 0; e < 4; e++) {
                float se = scl[mf * 16 + lkg * 4 + e];
                #pragma unroll
                for (int f = 0; f < 4; f++) acc[mf][f][e] *= se;
            }
        }

        if (tile < 15) {
            #pragma unroll
            for (int u = 0; u < 2; u++) {
                int e = t + u * 256;
                int d = e >> 6, j = e & 63;
                Kt[buf ^ 1][d][j] = k[((size_t)n * 8 + d) * L_ + (tile + 1) * 64 + j];
            }
        }

        int j0 = tile * 64;
        #pragma unroll
        for (int ks = 0; ks < 2; ks++) {
            f16x8 bh[4];
            #pragma unroll
            for (int f = 0; f < 4; f++) {
                size_t vbase = ((size_t)n * C_ + wv * 64 + f * 16 + lane16) * L_
                             + j0 + ks * 32 + lkg * 8;
                bh[f] = *reinterpret_cast<const f16x8*>(vth + vbase);
            }
            #pragma unroll
            for (int mf = 0; mf < 4; mf++) {
                int row = mf * 16 + lane16;
                int off = row * 128 + (((ks * 4 + lkg) ^ (row & 7)) << 4);
                f16x8 ah = *reinterpret_cast<const f16x8*>(&Ph[off]);
                #pragma unroll
                for (int f = 0; f < 4; f++)
                    acc[mf][f] = __builtin_amdgcn_mfma_f32_16x16x32_f16(ah, bh[f], acc[mf][f], 0, 0, 0);
            }
        }
    }

    psum += __shfl_xor(psum, 1);
    psum += __shfl_xor(psum, 2);
    if ((l & 3) == 0) sums[srow] = psum;
    __syncthreads();

    // epilogue phase A: registers -> fp16 tile in LDS pool [64][264]
    float g = gamma_nl_p[0];
    unsigned short* pool = (unsigned short*)smem;
    #pragma unroll
    for (int mf = 0; mf < 4; mf++) {
        #pragma unroll
        for (int e = 0; e < 4; e++) {
            int row = mf * 16 + lkg * 4 + e;
            int i = i0 + row;
            float rs = 1.0f / sums[row];
            int h = si * 32 + (i >> 5), w = sj * 32 + (i & 31);
            #pragma unroll
            for (int f = 0; f < 4; f++) {
                int c = wv * 64 + f * 16 + lane16;
                float xv = x[((size_t)(b * C_ + c)) * (H_ * W_) + (size_t)h * W_ + w];
                pool[row * 264 + c] = f16bits(g * (acc[mf][f][e] * rs) + xv);
            }
        }
    }
    __syncthreads();

    // epilogue phase B: coalesced 16B stores, full-line coverage
    #pragma unroll
    for (int u = 0; u < 8; u++) {
        int chunk = t + u * 256;              // 2048 chunks of 8 channels
        int row = chunk >> 5, cseg = (chunk & 31) * 8;
        int i = i0 + row;
        int h = si * 32 + (i >> 5), w = sj * 32 + (i & 31);
        size_t ci = (((size_t)b * H_ + h) * W_ + w) * C_ + cseg;
        *reinterpret_cast<uint4*>(&ctxh[ci]) =
            *reinterpret_cast<uint4*>(&pool[row * 264 + cseg]);
    }
}

// ---------------------------------------------------------------------------
// Kernel 4a: conv weight prep — fp16 hi/lo split, pre-swizzled B-frag order
// ---------------------------------------------------------------------------
__global__ __launch_bounds__(256) void wprep(
    const float* __restrict__ convW,
    unsigned short* __restrict__ WBh, unsigned short* __restrict__ WBl)
{
    int e = blockIdx.x * 256 + threadIdx.x;   // < 9*8*16*64*8 = 589824
    int j  = e & 7;
    int l  = (e >> 3) & 63;
    int cf = (e >> 9) & 15;
    int q  = (e >> 13) & 7;
    int tap = e >> 16;
    int co = cf * 16 + (l & 15);
    int ci = q * 32 + (l >> 4) * 8 + j;
    float v = convW[((size_t)co * C_ + ci) * 9 + tap];
    unsigned short hb = f16bits(v);
    WBh[e] = hb;
    WBl[e] = f16bits(v - f16tof(hb));
}

// ---------------------------------------------------------------------------
// Kernel 4b: 3x3 conv, fp16 ctx x hi/lo fp16 weights (2-term MFMA)
// block: (b, h-pair).  grid 512 x 256 threads (4 waves).
// ---------------------------------------------------------------------------
__global__ __launch_bounds__(256, 2) void conv_mfma(
    const unsigned short* __restrict__ ctxh,
    const unsigned short* __restrict__ WBh, const unsigned short* __restrict__ WBl,
    const float* __restrict__ convb, const float* __restrict__ bn_w,
    const float* __restrict__ bn_b, const float* __restrict__ bn_mean,
    const float* __restrict__ bn_var, const float* __restrict__ gamma_p,
    const float* __restrict__ x, float* __restrict__ out)
{
    // LDS: [hh(4)][wslot(66)][kgp(4)][16B], kg XOR-swizzled by (wslot>>1)&3
    __shared__ __align__(16) char Cs[1056 * 16];   // 16896 B
    int t = threadIdx.x;
    int l = t & 63, wv = t >> 6;
    int lrow = l & 15, lkg = l >> 4;
    int b = blockIdx.x >> 5;
    int h0 = (blockIdx.x & 31) * 2;

    float gmm = gamma_p[0];
    float sA[4], sB[4];
    #pragma unroll
    for (int f = 0; f < 4; f++) {
        int co = wv * 64 + f * 16 + lrow;
        float inv = bn_w[co] * rsqrtf(bn_var[co] + 1e-5f);
        sA[f] = gmm * inv;
        sB[f] = gmm * ((convb[co] - bn_mean[co]) * inv + bn_b[co]);
    }

    f32x4 acc[8][4];
    #pragma unroll
    for (int mf = 0; mf < 8; mf++)
        #pragma unroll
        for (int f = 0; f < 4; f++) acc[mf][f] = f32x4{0.f, 0.f, 0.f, 0.f};

    for (int q = 0; q < 8; q++) {
        int ci0 = q * 32;
        __syncthreads();
        for (int idx = t; idx < 1056; idx += 256) {
            int kgp = idx & 3;
            int rem = idx >> 2;                // hh*66 + wslot
            int wslot = rem % 66, hh = rem / 66;
            int h = h0 - 1 + hh, w = wslot - 1;
            int kg = kgp ^ ((wslot >> 1) & 3);
            uint4 v = uint4{0u, 0u, 0u, 0u};
            if ((unsigned)h < 64u && (unsigned)w < 64u)
                v = *reinterpret_cast<const uint4*>(
                    ctxh + ((((size_t)b * H_ + h) * W_ + w) * C_ + ci0 + kg * 8));
            *reinterpret_cast<uint4*>(&Cs[(rem * 4 + kgp) * 16]) = v;
        }
        __syncthreads();

        #pragma unroll
        for (int tap = 0; tap < 9; tap++) {
            const int kh = tap / 3, kw = tap % 3;
            f16x8 bh[4], bl[4];
            #pragma unroll
            for (int f = 0; f < 4; f++) {
                size_t base = ((((size_t)tap * 8 + q) * 16 + (wv * 4 + f)) * 64 + l) * 8;
                bh[f] = *reinterpret_cast<const f16x8*>(WBh + base);
                bl[f] = *reinterpret_cast<const f16x8*>(WBl + base);
            }
            #pragma unroll
            for (int mf = 0; mf < 8; mf++) {
                int wsl = (mf & 3) * 16 + lrow + kw;
                int hh = (mf >> 2) + kh;
                int kgp = lkg ^ ((wsl >> 1) & 3);
                int off = ((hh * 66 + wsl) * 4 + kgp) * 16;
                f16x8 ah = *reinterpret_cast<const f16x8*>(&Cs[off]);
                #pragma unroll
                for (int f = 0; f < 4; f++) {
                    acc[mf][f] = __builtin_amdgcn_mfma_f32_16x16x32_f16(ah, bh[f], acc[mf][f], 0, 0, 0);
                    acc[mf][f] = __builtin_amdgcn_mfma_f32_16x16x32_f16(ah, bl[f], acc[mf][f], 0, 0, 0);
                }
            }
        }
    }

    #pragma unroll
    for (int mf = 0; mf < 8; mf++) {
        int h = h0 + (mf >> 2);
        int wb = (mf & 3) * 16 + lkg * 4;
        #pragma unroll
        for (int f = 0; f < 4; f++) {
            int co = wv * 64 + f * 16 + lrow;
            size_t adr = (((size_t)b * C_ + co) * H_ + h) * W_ + wb;
            float4 xr = *reinterpret_cast<const float4*>(x + adr);
            float4 o;
            o.x = fmaxf(sA[f] * acc[mf][f][0] + sB[f] + xr.x, 0.f);
            o.y = fmaxf(sA[f] * acc[mf][f][1] + sB[f] + xr.y, 0.f);
            o.z = fmaxf(sA[f] * acc[mf][f][2] + sB[f] + xr.z, 0.f);
            o.w = fmaxf(sA[f] * acc[mf][f][3] + sB[f] + xr.w, 0.f);
            *reinterpret_cast<float4*>(out + adr) = o;
        }
    }
}

// ---------------------------------------------------------------------------
extern "C" void kernel_launch(void* const* d_in, const int* in_sizes, int n_in,
                              void* d_out, int out_size, void* d_ws, size_t ws_size,
                              hipStream_t stream)
{
    const float* x        = (const float*)d_in[0];
    const float* Wq       = (const float*)d_in[1];
    const float* bq       = (const float*)d_in[2];
    const float* Wk       = (const float*)d_in[3];
    const float* bk       = (const float*)d_in[4];
    const float* Wv       = (const float*)d_in[5];
    const float* bv       = (const float*)d_in[6];
    const float* gamma_nl = (const float*)d_in[7];
    const float* convW    = (const float*)d_in[8];
    const float* convb    = (const float*)d_in[9];
    const float* bn_w     = (const float*)d_in[10];
    const float* bn_b     = (const float*)d_in[11];
    const float* bn_mean  = (const float*)d_in[12];
    const float* bn_var   = (const float*)d_in[13];
    const float* gamma    = (const float*)d_in[14];
    float* out = (float*)d_out;

    float* q   = (float*)d_ws;                           // 524288 f32
    float* k   = q  + (size_t)N_ * 8 * L_;               // 524288 f32
    unsigned short* vth  = (unsigned short*)(k + (size_t)N_ * 8 * L_);
    unsigned short* ctxh = vth + (size_t)N_ * C_ * L_;
    unsigned short* WBh  = ctxh + (size_t)B_ * C_ * H_ * W_;
    unsigned short* WBl  = WBh + (size_t)9 * 8 * 16 * 64 * 8;
    unsigned short* WV2  = WBl + (size_t)9 * 8 * 16 * 64 * 8;

    wprep<<<dim3(589824 / 256), dim3(256), 0, stream>>>(convW, WBh, WBl);
    wprep2<<<dim3(65536 / 256), dim3(256), 0, stream>>>(Wv, WV2);
    qk_proj<<<dim3(N_ * L_ / 256), dim3(256), 0, stream>>>(x, Wq, bq, Wk, bk, q, k);
    v_proj_mfma<<<dim3(512), dim3(256), 0, stream>>>(x, WV2, bv, vth);
    attn_mfma<<<dim3(1024), dim3(256), 0, stream>>>(
        x, q, k, vth, gamma_nl, ctxh);
    conv_mfma<<<dim3(512), dim3(256), 0, stream>>>(
        ctxh, WBh, WBl, convb, bn_w, bn_b, bn_mean, bn_var, gamma, x, out);
}